// Round 1
// baseline (1236.669 us; speedup 1.0000x reference)
//
#include <hip/hip_runtime.h>
#include <hip/hip_fp16.h>
#include <cstdint>
#include <cstddef>

// Problem constants
constexpr int HD   = 512;          // hidden
constexpr int SQ   = 512;          // seq len
constexpr int NB   = 32;           // batch
constexpr int LAY  = 3;            // layers
constexpr int WID  = 4;            // conv width
constexpr int KIN  = (WID + 1) * HD;   // 2560
constexpr int PROW = SQ + 2 * WID;     // 520 padded rows
constexpr int MR   = NB * SQ;          // 16384 GEMM rows

typedef _Float16 f16x8 __attribute__((ext_vector_type(8)));
typedef float    f32x4 __attribute__((ext_vector_type(4)));

__device__ __forceinline__ void gld16(void* lds, const void* g) {
  __builtin_amdgcn_global_load_lds(
      (__attribute__((address_space(1))) void*)(g),
      (__attribute__((address_space(3))) void*)(lds),
      16, 0, 0);
}

// ---------------------------------------------------------------------------
// Weight transpose+convert: in fp32 [batch][R][C] -> out fp16 [batch][C][R]
// ---------------------------------------------------------------------------
__global__ void transpose_w(const float* __restrict__ in, _Float16* __restrict__ out,
                            int R, int C) {
  __shared__ float tile[32][33];
  const size_t base = (size_t)blockIdx.z * R * C;
  const int r0 = blockIdx.y * 32, c0 = blockIdx.x * 32;
  const int tx = threadIdx.x, ty = threadIdx.y;  // (32, 8)
#pragma unroll
  for (int j = 0; j < 32; j += 8)
    tile[ty + j][tx] = in[base + (size_t)(r0 + ty + j) * C + (c0 + tx)];
  __syncthreads();
#pragma unroll
  for (int j = 0; j < 32; j += 8)
    out[base + (size_t)(c0 + ty + j) * R + (r0 + tx)] = (_Float16)tile[tx][ty + j];
}

// ---------------------------------------------------------------------------
// Layer-0 interior: inputs fp32 [B][S][H] -> pad interiors (rows 4..515) fp16
// ---------------------------------------------------------------------------
__global__ void init_interior(const float4* __restrict__ in,
                              _Float16* __restrict__ padF, _Float16* __restrict__ padB) {
  const size_t idx = (size_t)blockIdx.x * 256 + threadIdx.x;  // over B*S*H/4
  float4 v = in[idx];
  const size_t e = idx * 4;
  const int h = (int)(e & (HD - 1));
  const size_t bt = e >> 9;
  const int t = (int)(bt & (SQ - 1));
  const int b = (int)(bt >> 9);
  const size_t o = ((size_t)(b * PROW + WID + t)) * HD + h;
  union { _Float16 hh[4]; uint2 u; } pk;
  pk.hh[0] = (_Float16)v.x; pk.hh[1] = (_Float16)v.y;
  pk.hh[2] = (_Float16)v.z; pk.hh[3] = (_Float16)v.w;
  *(uint2*)&padF[o] = pk.u;
  *(uint2*)&padB[o] = pk.u;
}

// ---------------------------------------------------------------------------
// Per-layer pad rows: rows 0..3 = fwd_pads[i], rows 516..519 = bwd_pads[i]
// (same values into both padF and padB, per reference)
// ---------------------------------------------------------------------------
__global__ void fill_pads(const float* __restrict__ fpad, const float* __restrict__ bpad,
                          _Float16* __restrict__ padF, _Float16* __restrict__ padB) {
  const int idx = blockIdx.x * 256 + threadIdx.x;  // 2^17 total
  const int h  = idx & (HD - 1);
  const int w  = (idx >> 9) & 3;
  const int b  = (idx >> 11) & 31;
  const int fb = idx >> 16;  // 0 = front pads, 1 = back pads
  const float v = fb ? bpad[w * HD + h] : fpad[w * HD + h];
  const int row = fb ? (SQ + WID + w) : w;
  const size_t o = ((size_t)(b * PROW + row)) * HD + h;
  const _Float16 hv = (_Float16)v;
  padF[o] = hv;
  padB[o] = hv;
}

// ---------------------------------------------------------------------------
// Windowed conv GEMM: t[m][n] = relu( sum_k pad[b][t + k/512 + off][k%512] *
//                                     W[k][n] + bias[n] )
// Wt is the transposed weight [512][2560] fp16. 128x128 tile, BK=32.
// grid: (4, 128, 2)  block: 256
// ---------------------------------------------------------------------------
__global__ __launch_bounds__(256)
void conv_gemm(const _Float16* __restrict__ padFp, const _Float16* __restrict__ padBp,
               const _Float16* __restrict__ WtF, const _Float16* __restrict__ WtB,
               const float* __restrict__ biasF, const float* __restrict__ biasB,
               _Float16* __restrict__ tF, _Float16* __restrict__ tB) {
  const int dir = blockIdx.z;
  const _Float16* pad = dir ? padBp : padFp;
  const _Float16* Wt  = dir ? WtB : WtF;
  const float* bias   = dir ? biasB : biasF;
  _Float16* outT      = dir ? tB : tF;
  const int off = dir ? WID : 0;

  const int m0 = blockIdx.y * 128;
  const int n0 = blockIdx.x * 128;
  const int b  = m0 >> 9;       // 512 rows per batch entry; tiles never straddle
  const int t0 = m0 & (SQ - 1);

  __shared__ alignas(16) _Float16 Asm[128 * 32];
  __shared__ alignas(16) _Float16 Bsm[128 * 32];

  const int tid  = threadIdx.x;
  const int lane = tid & 63, wv = tid >> 6;
  const int wr = (wv >> 1) * 64, wc = (wv & 1) * 64;
  const int lr = lane & 15, q = lane >> 4;
  const int ra = tid >> 2;            // staging row 0..63
  const int cc = (tid & 3) * 8;       // staging col chunk (elements)

  f32x4 acc[4][4] = {};

  const size_t arow0 = (size_t)(b * PROW + t0 + off);

  for (int k0 = 0; k0 < KIN; k0 += 32) {
    const int kseg = k0 >> 9;
    const int h0 = k0 & (HD - 1);
    const _Float16* Ab = pad + (arow0 + kseg) * (size_t)HD + h0;
    const _Float16* Bb = Wt + (size_t)n0 * KIN + k0;
    __syncthreads();
    gld16(&Asm[ra * 32 + cc],        Ab + (size_t)ra * HD + cc);
    gld16(&Asm[(ra + 64) * 32 + cc], Ab + (size_t)(ra + 64) * HD + cc);
    gld16(&Bsm[ra * 32 + cc],        Bb + (size_t)ra * KIN + cc);
    gld16(&Bsm[(ra + 64) * 32 + cc], Bb + (size_t)(ra + 64) * KIN + cc);
    __syncthreads();

    f16x8 af[4], bf[4];
#pragma unroll
    for (int r = 0; r < 4; ++r)
      af[r] = *(const f16x8*)&Asm[(wr + r * 16 + lr) * 32 + q * 8];
#pragma unroll
    for (int c = 0; c < 4; ++c)
      bf[c] = *(const f16x8*)&Bsm[(wc + c * 16 + lr) * 32 + q * 8];
#pragma unroll
    for (int r = 0; r < 4; ++r)
#pragma unroll
      for (int c = 0; c < 4; ++c)
        acc[r][c] = __builtin_amdgcn_mfma_f32_16x16x32_f16(af[r], bf[c], acc[r][c], 0, 0, 0);
  }

  // Epilogue: +bias, relu, store fp16
#pragma unroll
  for (int c = 0; c < 4; ++c) {
    const int ng = n0 + wc + c * 16 + lr;
    const float bv = bias[ng];
#pragma unroll
    for (int r = 0; r < 4; ++r) {
      const int mg = m0 + wr + r * 16 + q * 4;
#pragma unroll
      for (int g = 0; g < 4; ++g) {
        float v = acc[r][c][g] + bv;
        v = v > 0.f ? v : 0.f;
        outT[(size_t)(mg + g) * HD + ng] = (_Float16)v;
      }
    }
  }
}

// ---------------------------------------------------------------------------
// Highway GEMM + gate epilogue.
// proj = x @ W + b (W: [512][1024], transposed Wt: [1024][512]); nonlin = cols
// 0..511, gate = cols 512..1023; out = sig(gate)*x + (1-sig(gate))*relu(nonlin)
// Block computes a 128x64 nonlin tile AND its matching 128x64 gate tile.
// mode 0: write fp16 [16384][512] (oh). mode 1: write fp16 into pad interior
// (oh = pad buffer base) AND fp32 into out32 (+dir*512 column offset).
// grid: (8, 128, 2)  block: 256
// ---------------------------------------------------------------------------
__global__ __launch_bounds__(256)
void hw_gemm(const _Float16* __restrict__ xF, const _Float16* __restrict__ xB,
             const _Float16* __restrict__ WtFp, const _Float16* __restrict__ WtBp,
             const float* __restrict__ bFp, const float* __restrict__ bBp,
             _Float16* __restrict__ oFp, _Float16* __restrict__ oBp,
             float* __restrict__ out32, int mode) {
  const int dir = blockIdx.z;
  const _Float16* x  = dir ? xB : xF;
  const _Float16* Wt = dir ? WtBp : WtFp;
  const float* bias  = dir ? bBp : bFp;
  _Float16* oh       = dir ? oBp : oFp;

  const int m0 = blockIdx.y * 128;
  const int n0 = blockIdx.x * 64;

  __shared__ alignas(16) _Float16 Asm[128 * 32];
  __shared__ alignas(16) _Float16 Bn[64 * 32];
  __shared__ alignas(16) _Float16 Bg[64 * 32];

  const int tid  = threadIdx.x;
  const int lane = tid & 63, wv = tid >> 6;
  const int wr = (wv >> 1) * 64, wc = (wv & 1) * 32;
  const int lr = lane & 15, q = lane >> 4;
  const int ra = tid >> 2;
  const int cc = (tid & 3) * 8;

  f32x4 an[4][2] = {};
  f32x4 ag[4][2] = {};

  for (int k0 = 0; k0 < HD; k0 += 32) {
    const _Float16* Ab  = x + (size_t)m0 * HD + k0;
    const _Float16* Bnb = Wt + (size_t)n0 * HD + k0;
    const _Float16* Bgb = Wt + (size_t)(HD + n0) * HD + k0;
    __syncthreads();
    gld16(&Asm[ra * 32 + cc],        Ab + (size_t)ra * HD + cc);
    gld16(&Asm[(ra + 64) * 32 + cc], Ab + (size_t)(ra + 64) * HD + cc);
    gld16(&Bn[ra * 32 + cc],         Bnb + (size_t)ra * HD + cc);
    gld16(&Bg[ra * 32 + cc],         Bgb + (size_t)ra * HD + cc);
    __syncthreads();

    f16x8 af[4], bn[2], bg[2];
#pragma unroll
    for (int r = 0; r < 4; ++r)
      af[r] = *(const f16x8*)&Asm[(wr + r * 16 + lr) * 32 + q * 8];
#pragma unroll
    for (int c = 0; c < 2; ++c) {
      bn[c] = *(const f16x8*)&Bn[(wc + c * 16 + lr) * 32 + q * 8];
      bg[c] = *(const f16x8*)&Bg[(wc + c * 16 + lr) * 32 + q * 8];
    }
#pragma unroll
    for (int r = 0; r < 4; ++r)
#pragma unroll
      for (int c = 0; c < 2; ++c) {
        an[r][c] = __builtin_amdgcn_mfma_f32_16x16x32_f16(af[r], bn[c], an[r][c], 0, 0, 0);
        ag[r][c] = __builtin_amdgcn_mfma_f32_16x16x32_f16(af[r], bg[c], ag[r][c], 0, 0, 0);
      }
  }

#pragma unroll
  for (int c = 0; c < 2; ++c) {
    const int ng = n0 + wc + c * 16 + lr;       // 0..511
    const float bnv = bias[ng];
    const float bgv = bias[HD + ng];
#pragma unroll
    for (int r = 0; r < 4; ++r) {
      const int mg = m0 + wr + r * 16 + q * 4;
#pragma unroll
      for (int g = 0; g < 4; ++g) {
        const int row = mg + g;
        float nl = an[r][c][g] + bnv;
        nl = nl > 0.f ? nl : 0.f;
        const float gz = ag[r][c][g] + bgv;
        const float gate = 1.f / (1.f + __expf(-gz));
        const float xv = (float)x[(size_t)row * HD + ng];
        const float o = gate * xv + (1.f - gate) * nl;
        if (mode == 0) {
          oh[(size_t)row * HD + ng] = (_Float16)o;
        } else {
          const int bb = row >> 9, tt = row & (SQ - 1);
          oh[((size_t)(bb * PROW + WID + tt)) * HD + ng] = (_Float16)o;
          out32[(size_t)row * (2 * HD) + dir * HD + ng] = o;
        }
      }
    }
  }
}

// ---------------------------------------------------------------------------
extern "C" void kernel_launch(void* const* d_in, const int* in_sizes, int n_in,
                              void* d_out, int out_size, void* d_ws, size_t ws_size,
                              hipStream_t stream) {
  const float* inputs   = (const float*)d_in[0];
  // d_in[1] = mask (all ones, unused by reference math)
  const float* fwd_pads = (const float*)d_in[2];   // [3][4][512]
  const float* bwd_pads = (const float*)d_in[3];
  const float* fwd_W    = (const float*)d_in[4];   // [3][2560][512]
  const float* fwd_b    = (const float*)d_in[5];   // [3][512]
  const float* bwd_W    = (const float*)d_in[6];
  const float* bwd_b    = (const float*)d_in[7];
  const float* fwd_hw_W = (const float*)d_in[8];   // [3][2][512][1024]
  const float* fwd_hw_b = (const float*)d_in[9];   // [3][2][1024]
  const float* bwd_hw_W = (const float*)d_in[10];
  const float* bwd_hw_b = (const float*)d_in[11];
  float* out = (float*)d_out;

  char* p = (char*)d_ws;
  auto take = [&](size_t n) { char* r = p; p += (n + 255) & ~(size_t)255; return r; };

  _Float16* padF = (_Float16*)take((size_t)NB * PROW * HD * 2);
  _Float16* padB = (_Float16*)take((size_t)NB * PROW * HD * 2);
  _Float16* tF   = (_Float16*)take((size_t)MR * HD * 2);
  _Float16* tB   = (_Float16*)take((size_t)MR * HD * 2);
  _Float16* uF   = (_Float16*)take((size_t)MR * HD * 2);
  _Float16* uB   = (_Float16*)take((size_t)MR * HD * 2);
  _Float16* WtcF = (_Float16*)take((size_t)LAY * HD * KIN * 2);
  _Float16* WtcB = (_Float16*)take((size_t)LAY * HD * KIN * 2);
  _Float16* WthF = (_Float16*)take((size_t)LAY * 2 * (2 * HD) * HD * 2);
  _Float16* WthB = (_Float16*)take((size_t)LAY * 2 * (2 * HD) * HD * 2);

  // Weight transpose+convert (fp32 -> fp16, [R][C] -> [C][R] per batch slice)
  transpose_w<<<dim3(HD / 32, KIN / 32, LAY), dim3(32, 8), 0, stream>>>(fwd_W, WtcF, KIN, HD);
  transpose_w<<<dim3(HD / 32, KIN / 32, LAY), dim3(32, 8), 0, stream>>>(bwd_W, WtcB, KIN, HD);
  transpose_w<<<dim3((2 * HD) / 32, HD / 32, LAY * 2), dim3(32, 8), 0, stream>>>(fwd_hw_W, WthF, HD, 2 * HD);
  transpose_w<<<dim3((2 * HD) / 32, HD / 32, LAY * 2), dim3(32, 8), 0, stream>>>(bwd_hw_W, WthB, HD, 2 * HD);

  // Layer-0 activations into both pad interiors
  init_interior<<<(NB * SQ * HD / 4) / 256, 256, 0, stream>>>((const float4*)inputs, padF, padB);

  for (int i = 0; i < LAY; ++i) {
    fill_pads<<<512, 256, 0, stream>>>(fwd_pads + (size_t)i * WID * HD,
                                       bwd_pads + (size_t)i * WID * HD, padF, padB);
    conv_gemm<<<dim3(4, 128, 2), 256, 0, stream>>>(
        padF, padB,
        WtcF + (size_t)i * HD * KIN, WtcB + (size_t)i * HD * KIN,
        fwd_b + (size_t)i * HD, bwd_b + (size_t)i * HD, tF, tB);
    hw_gemm<<<dim3(8, 128, 2), 256, 0, stream>>>(
        tF, tB,
        WthF + (size_t)(i * 2 + 0) * (2 * HD) * HD, WthB + (size_t)(i * 2 + 0) * (2 * HD) * HD,
        fwd_hw_b + (size_t)(i * 2 + 0) * (2 * HD), bwd_hw_b + (size_t)(i * 2 + 0) * (2 * HD),
        uF, uB, nullptr, 0);
    hw_gemm<<<dim3(8, 128, 2), 256, 0, stream>>>(
        uF, uB,
        WthF + (size_t)(i * 2 + 1) * (2 * HD) * HD, WthB + (size_t)(i * 2 + 1) * (2 * HD) * HD,
        fwd_hw_b + (size_t)(i * 2 + 1) * (2 * HD), bwd_hw_b + (size_t)(i * 2 + 1) * (2 * HD),
        padF, padB, out + (size_t)i * MR * (2 * HD), 1);
  }
}

// Round 2
// 1070.950 us; speedup vs baseline: 1.1547x; 1.1547x over previous
//
#include <hip/hip_runtime.h>
#include <hip/hip_fp16.h>
#include <cstdint>
#include <cstddef>

// Problem constants
constexpr int HD   = 512;          // hidden
constexpr int SQ   = 512;          // seq len
constexpr int NB   = 32;           // batch
constexpr int LAY  = 3;            // layers
constexpr int WID  = 4;            // conv width
constexpr int KIN  = (WID + 1) * HD;   // 2560
constexpr int PROW = SQ + 2 * WID;     // 520 padded rows
constexpr int MR   = NB * SQ;          // 16384 GEMM rows

typedef _Float16 f16x8 __attribute__((ext_vector_type(8)));
typedef float    f32x4 __attribute__((ext_vector_type(4)));

__device__ __forceinline__ void gld16(void* lds, const void* g) {
  __builtin_amdgcn_global_load_lds(
      (__attribute__((address_space(1))) void*)(g),
      (__attribute__((address_space(3))) void*)(lds),
      16, 0, 0);
}

// ---------------------------------------------------------------------------
// Weight transpose+convert: in fp32 [batch][R][C] -> out fp16 [batch][C][R]
// ---------------------------------------------------------------------------
__global__ void transpose_w(const float* __restrict__ in, _Float16* __restrict__ out,
                            int R, int C) {
  __shared__ float tile[32][33];
  const size_t base = (size_t)blockIdx.z * R * C;
  const int r0 = blockIdx.y * 32, c0 = blockIdx.x * 32;
  const int tx = threadIdx.x, ty = threadIdx.y;  // (32, 8)
#pragma unroll
  for (int j = 0; j < 32; j += 8)
    tile[ty + j][tx] = in[base + (size_t)(r0 + ty + j) * C + (c0 + tx)];
  __syncthreads();
#pragma unroll
  for (int j = 0; j < 32; j += 8)
    out[base + (size_t)(c0 + ty + j) * R + (r0 + tx)] = (_Float16)tile[tx][ty + j];
}

// ---------------------------------------------------------------------------
// Layer-0 interior: inputs fp32 [B][S][H] -> pad interiors (rows 4..515) fp16
// ---------------------------------------------------------------------------
__global__ void init_interior(const float4* __restrict__ in,
                              _Float16* __restrict__ padF, _Float16* __restrict__ padB) {
  const size_t idx = (size_t)blockIdx.x * 256 + threadIdx.x;  // over B*S*H/4
  float4 v = in[idx];
  const size_t e = idx * 4;
  const int h = (int)(e & (HD - 1));
  const size_t bt = e >> 9;
  const int t = (int)(bt & (SQ - 1));
  const int b = (int)(bt >> 9);
  const size_t o = ((size_t)(b * PROW + WID + t)) * HD + h;
  union { _Float16 hh[4]; uint2 u; } pk;
  pk.hh[0] = (_Float16)v.x; pk.hh[1] = (_Float16)v.y;
  pk.hh[2] = (_Float16)v.z; pk.hh[3] = (_Float16)v.w;
  *(uint2*)&padF[o] = pk.u;
  *(uint2*)&padB[o] = pk.u;
}

// ---------------------------------------------------------------------------
// Per-layer pad rows: rows 0..3 = fwd_pads[i], rows 516..519 = bwd_pads[i]
// ---------------------------------------------------------------------------
__global__ void fill_pads(const float* __restrict__ fpad, const float* __restrict__ bpad,
                          _Float16* __restrict__ padF, _Float16* __restrict__ padB) {
  const int idx = blockIdx.x * 256 + threadIdx.x;  // 2^17 total
  const int h  = idx & (HD - 1);
  const int w  = (idx >> 9) & 3;
  const int b  = (idx >> 11) & 31;
  const int fb = idx >> 16;  // 0 = front pads, 1 = back pads
  const float v = fb ? bpad[w * HD + h] : fpad[w * HD + h];
  const int row = fb ? (SQ + WID + w) : w;
  const size_t o = ((size_t)(b * PROW + row)) * HD + h;
  const _Float16 hv = (_Float16)v;
  padF[o] = hv;
  padB[o] = hv;
}

// ---------------------------------------------------------------------------
// Windowed conv GEMM, BK=64, XOR-swizzled LDS, XCD-aware block mapping.
// grid: 1024 blocks (1D). dir = (id&7)>>2: fwd on XCD 0-3, bwd on XCD 4-7;
// the 4 n-tiles of an m-tile are consecutive slots on ONE xcd (A L2 reuse).
// ---------------------------------------------------------------------------
__global__ __launch_bounds__(256)
void conv_gemm(const _Float16* __restrict__ padFp, const _Float16* __restrict__ padBp,
               const _Float16* __restrict__ WtF, const _Float16* __restrict__ WtB,
               const float* __restrict__ biasF, const float* __restrict__ biasB,
               _Float16* __restrict__ tF, _Float16* __restrict__ tB) {
  const int id   = blockIdx.x;
  const int xcd  = id & 7;
  const int dir  = xcd >> 2;          // 0 = fwd (XCD 0-3), 1 = bwd (XCD 4-7)
  const int xl   = xcd & 3;
  const int slot = id >> 3;           // 0..127
  const int nt   = slot & 3;          // 4 n-tiles, consecutive on same XCD
  const int mg   = slot >> 2;         // 0..31
  const int mt   = xl + 4 * mg;       // 0..127

  const _Float16* pad = dir ? padBp : padFp;
  const _Float16* Wt  = dir ? WtB : WtF;
  const float* bias   = dir ? biasB : biasF;
  _Float16* outT      = dir ? tB : tF;
  const int off = dir ? WID : 0;

  const int m0 = mt * 128;
  const int n0 = nt * 128;
  const int b  = m0 >> 9;
  const int t0 = m0 & (SQ - 1);

  __shared__ alignas(16) _Float16 Asm[128 * 64];
  __shared__ alignas(16) _Float16 Bsm[128 * 64];

  const int tid  = threadIdx.x;
  const int lane = tid & 63, wv = tid >> 6;
  const int wr = (wv >> 1) * 64, wc = (wv & 1) * 64;
  const int lr = lane & 15, q = lane >> 4;
  const int srow = tid >> 3;                 // staging row 0..31 (per 32-row group)
  const int clog = (tid & 7) ^ (srow & 7);   // logical 16B chunk for this lane
  const int goff = clog * 8;                 // element offset within row

  f32x4 acc[4][4] = {};

  const size_t arow0 = (size_t)(b * PROW + t0 + off);

#pragma unroll 2
  for (int k0 = 0; k0 < KIN; k0 += 64) {
    const int kseg = k0 >> 9;
    const int h0 = k0 & (HD - 1);
    const _Float16* Ab = pad + (arow0 + kseg) * (size_t)HD + h0;
    const _Float16* Bb = Wt + (size_t)n0 * KIN + k0;
    __syncthreads();
#pragma unroll
    for (int j = 0; j < 4; ++j) {
      gld16(&Asm[j * 2048 + tid * 8], Ab + (size_t)(j * 32 + srow) * HD + goff);
      gld16(&Bsm[j * 2048 + tid * 8], Bb + (size_t)(j * 32 + srow) * KIN + goff);
    }
    __syncthreads();

#pragma unroll
    for (int h = 0; h < 2; ++h) {
      f16x8 af[4], bf[4];
#pragma unroll
      for (int r = 0; r < 4; ++r) {
        const int row = wr + r * 16 + lr;
        const int ch = ((h << 2) | q) ^ (lr & 7);
        af[r] = *(const f16x8*)&Asm[row * 64 + ch * 8];
      }
#pragma unroll
      for (int c = 0; c < 4; ++c) {
        const int row = wc + c * 16 + lr;
        const int ch = ((h << 2) | q) ^ (lr & 7);
        bf[c] = *(const f16x8*)&Bsm[row * 64 + ch * 8];
      }
#pragma unroll
      for (int r = 0; r < 4; ++r)
#pragma unroll
        for (int c = 0; c < 4; ++c)
          acc[r][c] = __builtin_amdgcn_mfma_f32_16x16x32_f16(af[r], bf[c], acc[r][c], 0, 0, 0);
    }
  }

  // Epilogue: +bias, relu, store fp16
#pragma unroll
  for (int c = 0; c < 4; ++c) {
    const int ng = n0 + wc + c * 16 + lr;
    const float bv = bias[ng];
#pragma unroll
    for (int r = 0; r < 4; ++r) {
      const int mg2 = m0 + wr + r * 16 + q * 4;
#pragma unroll
      for (int g = 0; g < 4; ++g) {
        float v = acc[r][c][g] + bv;
        v = v > 0.f ? v : 0.f;
        outT[(size_t)(mg2 + g) * HD + ng] = (_Float16)v;
      }
    }
  }
}

// ---------------------------------------------------------------------------
// Highway GEMM + gate epilogue. BK=64, XOR-swizzled LDS, XCD-aware mapping.
// Block computes 128x64 nonlin tile AND matching 128x64 gate tile.
// x-subtile for the epilogue is captured from Asm at the k0==n0 iteration.
// grid: 2048 blocks (1D).
// ---------------------------------------------------------------------------
__global__ __launch_bounds__(256)
void hw_gemm(const _Float16* __restrict__ xF, const _Float16* __restrict__ xB,
             const _Float16* __restrict__ WtFp, const _Float16* __restrict__ WtBp,
             const float* __restrict__ bFp, const float* __restrict__ bBp,
             _Float16* __restrict__ oFp, _Float16* __restrict__ oBp,
             float* __restrict__ out32, int mode) {
  const int id   = blockIdx.x;
  const int xcd  = id & 7;
  const int dir  = xcd >> 2;
  const int xl   = xcd & 3;
  const int slot = id >> 3;           // 0..255
  const int nt   = slot & 7;          // 8 n-tiles of 64, consecutive on same XCD
  const int mg   = slot >> 3;         // 0..31
  const int mt   = xl + 4 * mg;       // 0..127

  const _Float16* x  = dir ? xB : xF;
  const _Float16* Wt = dir ? WtBp : WtFp;
  const float* bias  = dir ? bBp : bFp;
  _Float16* oh       = dir ? oBp : oFp;

  const int m0 = mt * 128;
  const int n0 = nt * 64;

  __shared__ alignas(16) _Float16 Asm[128 * 64];
  __shared__ alignas(16) _Float16 Bn[64 * 64];
  __shared__ alignas(16) _Float16 Bg[64 * 64];

  const int tid  = threadIdx.x;
  const int lane = tid & 63, wv = tid >> 6;
  const int wr = (wv >> 1) * 64, wc = (wv & 1) * 32;
  const int lr = lane & 15, q = lane >> 4;
  const int srow = tid >> 3;
  const int clog = (tid & 7) ^ (srow & 7);
  const int goff = clog * 8;

  f32x4 an[4][2] = {};
  f32x4 ag[4][2] = {};
  _Float16 xv[4][2][4] = {};

  for (int k0 = 0; k0 < HD; k0 += 64) {
    const _Float16* Ab  = x + (size_t)m0 * HD + k0;
    const _Float16* Bnb = Wt + (size_t)n0 * HD + k0;
    const _Float16* Bgb = Wt + (size_t)(HD + n0) * HD + k0;
    __syncthreads();
#pragma unroll
    for (int j = 0; j < 4; ++j)
      gld16(&Asm[j * 2048 + tid * 8], Ab + (size_t)(j * 32 + srow) * HD + goff);
#pragma unroll
    for (int j = 0; j < 2; ++j) {
      gld16(&Bn[j * 2048 + tid * 8], Bnb + (size_t)(j * 32 + srow) * HD + goff);
      gld16(&Bg[j * 2048 + tid * 8], Bgb + (size_t)(j * 32 + srow) * HD + goff);
    }
    __syncthreads();

    if (k0 == n0) {
      // x[m0+row][n0+col] for the epilogue lives in Asm right now
#pragma unroll
      for (int r = 0; r < 4; ++r)
#pragma unroll
        for (int c = 0; c < 2; ++c)
#pragma unroll
          for (int g = 0; g < 4; ++g) {
            const int row = wr + r * 16 + q * 4 + g;
            const int col = wc + c * 16 + lr;
            xv[r][c][g] = Asm[row * 64 + ((((col >> 3) ^ (row & 7)) << 3) | (col & 7))];
          }
    }

#pragma unroll
    for (int h = 0; h < 2; ++h) {
      f16x8 af[4], bn[2], bg[2];
#pragma unroll
      for (int r = 0; r < 4; ++r) {
        const int row = wr + r * 16 + lr;
        const int ch = ((h << 2) | q) ^ (lr & 7);
        af[r] = *(const f16x8*)&Asm[row * 64 + ch * 8];
      }
#pragma unroll
      for (int c = 0; c < 2; ++c) {
        const int row = wc + c * 16 + lr;
        const int ch = ((h << 2) | q) ^ (lr & 7);
        bn[c] = *(const f16x8*)&Bn[row * 64 + ch * 8];
        bg[c] = *(const f16x8*)&Bg[row * 64 + ch * 8];
      }
#pragma unroll
      for (int r = 0; r < 4; ++r)
#pragma unroll
        for (int c = 0; c < 2; ++c) {
          an[r][c] = __builtin_amdgcn_mfma_f32_16x16x32_f16(af[r], bn[c], an[r][c], 0, 0, 0);
          ag[r][c] = __builtin_amdgcn_mfma_f32_16x16x32_f16(af[r], bg[c], ag[r][c], 0, 0, 0);
        }
    }
  }

#pragma unroll
  for (int c = 0; c < 2; ++c) {
    const int ng = n0 + wc + c * 16 + lr;       // 0..511
    const float bnv = bias[ng];
    const float bgv = bias[HD + ng];
#pragma unroll
    for (int r = 0; r < 4; ++r) {
      const int mg2 = m0 + wr + r * 16 + q * 4;
#pragma unroll
      for (int g = 0; g < 4; ++g) {
        const int row = mg2 + g;
        float nl = an[r][c][g] + bnv;
        nl = nl > 0.f ? nl : 0.f;
        const float gz = ag[r][c][g] + bgv;
        const float gate = 1.f / (1.f + __expf(-gz));
        const float xvf = (float)xv[r][c][g];
        const float o = gate * xvf + (1.f - gate) * nl;
        if (mode == 0) {
          oh[(size_t)row * HD + ng] = (_Float16)o;
        } else {
          const int bb = row >> 9, tt = row & (SQ - 1);
          oh[((size_t)(bb * PROW + WID + tt)) * HD + ng] = (_Float16)o;
          out32[(size_t)row * (2 * HD) + dir * HD + ng] = o;
        }
      }
    }
  }
}

// ---------------------------------------------------------------------------
extern "C" void kernel_launch(void* const* d_in, const int* in_sizes, int n_in,
                              void* d_out, int out_size, void* d_ws, size_t ws_size,
                              hipStream_t stream) {
  const float* inputs   = (const float*)d_in[0];
  // d_in[1] = mask (all ones, unused by reference math)
  const float* fwd_pads = (const float*)d_in[2];   // [3][4][512]
  const float* bwd_pads = (const float*)d_in[3];
  const float* fwd_W    = (const float*)d_in[4];   // [3][2560][512]
  const float* fwd_b    = (const float*)d_in[5];   // [3][512]
  const float* bwd_W    = (const float*)d_in[6];
  const float* bwd_b    = (const float*)d_in[7];
  const float* fwd_hw_W = (const float*)d_in[8];   // [3][2][512][1024]
  const float* fwd_hw_b = (const float*)d_in[9];   // [3][2][1024]
  const float* bwd_hw_W = (const float*)d_in[10];
  const float* bwd_hw_b = (const float*)d_in[11];
  float* out = (float*)d_out;

  char* p = (char*)d_ws;
  auto take = [&](size_t n) { char* r = p; p += (n + 255) & ~(size_t)255; return r; };

  _Float16* padF = (_Float16*)take((size_t)NB * PROW * HD * 2);
  _Float16* padB = (_Float16*)take((size_t)NB * PROW * HD * 2);
  _Float16* tF   = (_Float16*)take((size_t)MR * HD * 2);
  _Float16* tB   = (_Float16*)take((size_t)MR * HD * 2);
  _Float16* uF   = (_Float16*)take((size_t)MR * HD * 2);
  _Float16* uB   = (_Float16*)take((size_t)MR * HD * 2);
  _Float16* WtcF = (_Float16*)take((size_t)LAY * HD * KIN * 2);
  _Float16* WtcB = (_Float16*)take((size_t)LAY * HD * KIN * 2);
  _Float16* WthF = (_Float16*)take((size_t)LAY * 2 * (2 * HD) * HD * 2);
  _Float16* WthB = (_Float16*)take((size_t)LAY * 2 * (2 * HD) * HD * 2);

  // Weight transpose+convert (fp32 -> fp16, [R][C] -> [C][R] per batch slice)
  transpose_w<<<dim3(HD / 32, KIN / 32, LAY), dim3(32, 8), 0, stream>>>(fwd_W, WtcF, KIN, HD);
  transpose_w<<<dim3(HD / 32, KIN / 32, LAY), dim3(32, 8), 0, stream>>>(bwd_W, WtcB, KIN, HD);
  transpose_w<<<dim3((2 * HD) / 32, HD / 32, LAY * 2), dim3(32, 8), 0, stream>>>(fwd_hw_W, WthF, HD, 2 * HD);
  transpose_w<<<dim3((2 * HD) / 32, HD / 32, LAY * 2), dim3(32, 8), 0, stream>>>(bwd_hw_W, WthB, HD, 2 * HD);

  // Layer-0 activations into both pad interiors
  init_interior<<<(NB * SQ * HD / 4) / 256, 256, 0, stream>>>((const float4*)inputs, padF, padB);

  for (int i = 0; i < LAY; ++i) {
    fill_pads<<<512, 256, 0, stream>>>(fwd_pads + (size_t)i * WID * HD,
                                       bwd_pads + (size_t)i * WID * HD, padF, padB);
    conv_gemm<<<dim3(1024), 256, 0, stream>>>(
        padF, padB,
        WtcF + (size_t)i * HD * KIN, WtcB + (size_t)i * HD * KIN,
        fwd_b + (size_t)i * HD, bwd_b + (size_t)i * HD, tF, tB);
    hw_gemm<<<dim3(2048), 256, 0, stream>>>(
        tF, tB,
        WthF + (size_t)(i * 2 + 0) * (2 * HD) * HD, WthB + (size_t)(i * 2 + 0) * (2 * HD) * HD,
        fwd_hw_b + (size_t)(i * 2 + 0) * (2 * HD), bwd_hw_b + (size_t)(i * 2 + 0) * (2 * HD),
        uF, uB, nullptr, 0);
    hw_gemm<<<dim3(2048), 256, 0, stream>>>(
        uF, uB,
        WthF + (size_t)(i * 2 + 1) * (2 * HD) * HD, WthB + (size_t)(i * 2 + 1) * (2 * HD) * HD,
        fwd_hw_b + (size_t)(i * 2 + 1) * (2 * HD), bwd_hw_b + (size_t)(i * 2 + 1) * (2 * HD),
        padF, padB, out + (size_t)i * MR * (2 * HD), 1);
  }
}

// Round 3
// 981.109 us; speedup vs baseline: 1.2605x; 1.0916x over previous
//
#include <hip/hip_runtime.h>
#include <hip/hip_fp16.h>
#include <cstdint>
#include <cstddef>

// Problem constants
constexpr int HD   = 512;          // hidden
constexpr int SQ   = 512;          // seq len
constexpr int NB   = 32;           // batch
constexpr int LAY  = 3;            // layers
constexpr int WID  = 4;            // conv width
constexpr int KIN  = (WID + 1) * HD;   // 2560
constexpr int PROW = SQ + 2 * WID;     // 520 padded rows
constexpr int MR   = NB * SQ;          // 16384 GEMM rows
constexpr int PSTR = NB * PROW * HD;   // pad buffer stride (elems)

typedef _Float16 f16x8 __attribute__((ext_vector_type(8)));
typedef float    f32x4 __attribute__((ext_vector_type(4)));

__device__ __forceinline__ void gld16(void* lds, const void* g) {
  __builtin_amdgcn_global_load_lds(
      (__attribute__((address_space(1))) void*)(g),
      (__attribute__((address_space(3))) void*)(lds),
      16, 0, 0);
}

// ---------------------------------------------------------------------------
// Paired weight transpose+convert: fp32 [nsl][R][C] x2 -> fp16 [nsl][C][R] x2
// z < nsl handles the fwd tensor, z >= nsl the bwd tensor.
// ---------------------------------------------------------------------------
__global__ void transpose_w2(const float* __restrict__ inF, const float* __restrict__ inB,
                             _Float16* __restrict__ outF, _Float16* __restrict__ outB,
                             int R, int C, int nsl) {
  __shared__ float tile[32][33];
  const int z = blockIdx.z;
  const float* in = (z < nsl) ? inF : inB;
  _Float16* out   = (z < nsl) ? outF : outB;
  const int sl    = (z < nsl) ? z : z - nsl;
  const size_t base = (size_t)sl * R * C;
  const int r0 = blockIdx.y * 32, c0 = blockIdx.x * 32;
  const int tx = threadIdx.x, ty = threadIdx.y;  // (32, 8)
#pragma unroll
  for (int j = 0; j < 32; j += 8)
    tile[ty + j][tx] = in[base + (size_t)(r0 + ty + j) * C + (c0 + tx)];
  __syncthreads();
#pragma unroll
  for (int j = 0; j < 32; j += 8)
    out[base + (size_t)(c0 + ty + j) * R + (r0 + tx)] = (_Float16)tile[tx][ty + j];
}

// ---------------------------------------------------------------------------
// Layer-0 interior: inputs fp32 [B][S][H] -> layer-0 pad interiors fp16
// ---------------------------------------------------------------------------
__global__ void init_interior(const float4* __restrict__ in,
                              _Float16* __restrict__ padF, _Float16* __restrict__ padB) {
  const size_t idx = (size_t)blockIdx.x * 256 + threadIdx.x;  // over B*S*H/4
  float4 v = in[idx];
  const size_t e = idx * 4;
  const int h = (int)(e & (HD - 1));
  const size_t bt = e >> 9;
  const int t = (int)(bt & (SQ - 1));
  const int b = (int)(bt >> 9);
  const size_t o = ((size_t)(b * PROW + WID + t)) * HD + h;
  union { _Float16 hh[4]; uint2 u; } pk;
  pk.hh[0] = (_Float16)v.x; pk.hh[1] = (_Float16)v.y;
  pk.hh[2] = (_Float16)v.z; pk.hh[3] = (_Float16)v.w;
  *(uint2*)&padF[o] = pk.u;
  *(uint2*)&padB[o] = pk.u;
}

// ---------------------------------------------------------------------------
// Fill border rows of ALL 3 layers' pad buffers once.
// rows 0..3 = fwd_pads[l], rows 516..519 = bwd_pads[l] (into both padF, padB)
// ---------------------------------------------------------------------------
__global__ void fill_all_pads(const float* __restrict__ fpads, const float* __restrict__ bpads,
                              _Float16* __restrict__ padF, _Float16* __restrict__ padB) {
  const int idx = blockIdx.x * 256 + threadIdx.x;  // 3*2^17 total
  const int h  = idx & (HD - 1);
  const int w  = (idx >> 9) & 3;
  const int b  = (idx >> 11) & 31;
  const int fb = (idx >> 16) & 1;  // 0 = front pads, 1 = back pads
  const int l  = idx >> 17;        // layer
  const float v = fb ? bpads[l * WID * HD + w * HD + h] : fpads[l * WID * HD + w * HD + h];
  const int row = fb ? (SQ + WID + w) : w;
  const size_t o = (size_t)l * PSTR + ((size_t)(b * PROW + row)) * HD + h;
  const _Float16 hv = (_Float16)v;
  padF[o] = hv;
  padB[o] = hv;
}

// ---------------------------------------------------------------------------
// Windowed conv GEMM, BK=64, XOR-swizzled LDS, XCD-aware block mapping,
// vectorized epilogue (LDS transpose -> dwordx4 stores).
// grid: 1024 blocks (1D).
// ---------------------------------------------------------------------------
__global__ __launch_bounds__(256)
void conv_gemm(const _Float16* __restrict__ padFp, const _Float16* __restrict__ padBp,
               const _Float16* __restrict__ WtF, const _Float16* __restrict__ WtB,
               const float* __restrict__ biasF, const float* __restrict__ biasB,
               _Float16* __restrict__ tF, _Float16* __restrict__ tB) {
  const int id   = blockIdx.x;
  const int xcd  = id & 7;
  const int dir  = xcd >> 2;          // 0 = fwd (XCD 0-3), 1 = bwd (XCD 4-7)
  const int xl   = xcd & 3;
  const int slot = id >> 3;           // 0..127
  const int nt   = slot & 3;          // 4 n-tiles, consecutive on same XCD
  const int mg   = slot >> 2;         // 0..31
  const int mt   = xl + 4 * mg;       // 0..127

  const _Float16* pad = dir ? padBp : padFp;
  const _Float16* Wt  = dir ? WtB : WtF;
  const float* bias   = dir ? biasB : biasF;
  _Float16* outT      = dir ? tB : tF;
  const int off = dir ? WID : 0;

  const int m0 = mt * 128;
  const int n0 = nt * 128;
  const int b  = m0 >> 9;
  const int t0 = m0 & (SQ - 1);

  __shared__ alignas(16) _Float16 SM[128 * 128];   // 32 KB
  _Float16* Asm = SM;            // 128x64
  _Float16* Bsm = SM + 8192;     // 128x64

  const int tid  = threadIdx.x;
  const int lane = tid & 63, wv = tid >> 6;
  const int wr = (wv >> 1) * 64, wc = (wv & 1) * 64;
  const int lr = lane & 15, q = lane >> 4;
  const int srow = tid >> 3;                 // staging row 0..31 (per 32-row group)
  const int clog = (tid & 7) ^ (srow & 7);   // logical 16B chunk for this lane
  const int goff = clog * 8;                 // element offset within row

  f32x4 acc[4][4] = {};

  const size_t arow0 = (size_t)(b * PROW + t0 + off);

#pragma unroll 2
  for (int k0 = 0; k0 < KIN; k0 += 64) {
    const int kseg = k0 >> 9;
    const int h0 = k0 & (HD - 1);
    const _Float16* Ab = pad + (arow0 + kseg) * (size_t)HD + h0;
    const _Float16* Bb = Wt + (size_t)n0 * KIN + k0;
    __syncthreads();
#pragma unroll
    for (int j = 0; j < 4; ++j) {
      gld16(&Asm[j * 2048 + tid * 8], Ab + (size_t)(j * 32 + srow) * HD + goff);
      gld16(&Bsm[j * 2048 + tid * 8], Bb + (size_t)(j * 32 + srow) * KIN + goff);
    }
    __syncthreads();

#pragma unroll
    for (int h = 0; h < 2; ++h) {
      f16x8 af[4], bf[4];
      const int ch = ((h << 2) | q) ^ (lr & 7);
#pragma unroll
      for (int r = 0; r < 4; ++r)
        af[r] = *(const f16x8*)&Asm[(wr + r * 16 + lr) * 64 + ch * 8];
#pragma unroll
      for (int c = 0; c < 4; ++c)
        bf[c] = *(const f16x8*)&Bsm[(wc + c * 16 + lr) * 64 + ch * 8];
#pragma unroll
      for (int r = 0; r < 4; ++r)
#pragma unroll
        for (int c = 0; c < 4; ++c)
          acc[r][c] = __builtin_amdgcn_mfma_f32_16x16x32_f16(af[r], bf[c], acc[r][c], 0, 0, 0);
    }
  }

  // Epilogue: +bias, relu -> LDS transpose (xor-swizzled) -> vector stores
  __syncthreads();
#pragma unroll
  for (int c = 0; c < 4; ++c) {
    const int col = wc + c * 16 + lr;          // 0..127
    const float bv = bias[n0 + col];
#pragma unroll
    for (int r = 0; r < 4; ++r)
#pragma unroll
      for (int g = 0; g < 4; ++g) {
        const int row = wr + r * 16 + q * 4 + g;  // 0..127
        const int pc = (col >> 3) ^ (row & 7);
        float v = acc[r][c][g] + bv;
        v = v > 0.f ? v : 0.f;
        SM[row * 128 + pc * 8 + (col & 7)] = (_Float16)v;
      }
  }
  __syncthreads();
#pragma unroll
  for (int j = 0; j < 8; ++j) {
    const int cid = j * 256 + tid;
    const int row = cid >> 4;        // 0..127
    const int gc = cid & 15;
    const int pc = gc ^ (row & 7);
    f16x8 v8 = *(const f16x8*)&SM[row * 128 + pc * 8];
    *(f16x8*)&outT[(size_t)(m0 + row) * HD + n0 + gc * 8] = v8;
  }
}

// ---------------------------------------------------------------------------
// Highway GEMM + gate epilogue. Tile 256 rows x 64 out-cols (256x128 proj).
// BK=64, XOR-swizzled LDS, XCD-aware mapping, vectorized epilogue.
// mode 0: write fp16 [16384][512] (oh). mode 1: write fp16 into NEXT layer's
// pad interior AND fp32 into out32. mode 2: fp32 out32 only (last layer).
// grid: 1024 blocks (1D).
// ---------------------------------------------------------------------------
__global__ __launch_bounds__(256)
void hw_gemm(const _Float16* __restrict__ xF, const _Float16* __restrict__ xB,
             const _Float16* __restrict__ WtFp, const _Float16* __restrict__ WtBp,
             const float* __restrict__ bFp, const float* __restrict__ bBp,
             _Float16* __restrict__ oFp, _Float16* __restrict__ oBp,
             float* __restrict__ out32, int mode) {
  const int id   = blockIdx.x;
  const int xcd  = id & 7;
  const int dir  = xcd >> 2;
  const int xl   = xcd & 3;
  const int slot = id >> 3;           // 0..127
  const int nt   = slot & 7;          // 8 n-tiles of 64, consecutive on same XCD
  const int mg   = slot >> 3;         // 0..15
  const int mt   = xl + 4 * mg;       // 0..63

  const _Float16* x  = dir ? xB : xF;
  const _Float16* Wt = dir ? WtBp : WtFp;
  const float* bias  = dir ? bBp : bFp;
  _Float16* oh       = dir ? oBp : oFp;

  const int m0 = mt * 256;
  const int n0 = nt * 64;

  __shared__ alignas(16) _Float16 SM[32768];   // 64 KB
  _Float16* Asm = SM;            // 16384 (256x64)
  _Float16* Bn  = SM + 16384;    // 4096
  _Float16* Bg  = SM + 20480;    // 4096
  // epilogue: S0 = SM[0..16384) (nonlin), S1 = SM[16384..32768) (gate z)

  const int tid  = threadIdx.x;
  const int lane = tid & 63, wv = tid >> 6;
  const int lr = lane & 15, q = lane >> 4;
  const int srow = tid >> 3;
  const int clog = (tid & 7) ^ (srow & 7);
  const int goff = clog * 8;

  f32x4 an[4][4] = {};
  f32x4 ag[4][4] = {};

#pragma unroll 2
  for (int k0 = 0; k0 < HD; k0 += 64) {
    const _Float16* Ab  = x + (size_t)m0 * HD + k0;
    const _Float16* Bnb = Wt + (size_t)n0 * HD + k0;
    const _Float16* Bgb = Wt + (size_t)(HD + n0) * HD + k0;
    __syncthreads();
#pragma unroll
    for (int j = 0; j < 8; ++j)
      gld16(&Asm[j * 2048 + tid * 8], Ab + (size_t)(j * 32 + srow) * HD + goff);
#pragma unroll
    for (int j = 0; j < 2; ++j) {
      gld16(&Bn[j * 2048 + tid * 8], Bnb + (size_t)(j * 32 + srow) * HD + goff);
      gld16(&Bg[j * 2048 + tid * 8], Bgb + (size_t)(j * 32 + srow) * HD + goff);
    }
    __syncthreads();

#pragma unroll
    for (int h = 0; h < 2; ++h) {
      const int ch = ((h << 2) | q) ^ (lr & 7);
      f16x8 af[4], bn[4], bg[4];
#pragma unroll
      for (int r = 0; r < 4; ++r)
        af[r] = *(const f16x8*)&Asm[(wv * 64 + r * 16 + lr) * 64 + ch * 8];
#pragma unroll
      for (int c = 0; c < 4; ++c) {
        bn[c] = *(const f16x8*)&Bn[(c * 16 + lr) * 64 + ch * 8];
        bg[c] = *(const f16x8*)&Bg[(c * 16 + lr) * 64 + ch * 8];
      }
#pragma unroll
      for (int r = 0; r < 4; ++r)
#pragma unroll
        for (int c = 0; c < 4; ++c) {
          an[r][c] = __builtin_amdgcn_mfma_f32_16x16x32_f16(af[r], bn[c], an[r][c], 0, 0, 0);
          ag[r][c] = __builtin_amdgcn_mfma_f32_16x16x32_f16(af[r], bg[c], ag[r][c], 0, 0, 0);
        }
    }
  }

  // Epilogue: scatter nonlin/gate to LDS (xor-swizzled), then vectorized
  // readback: combine with x (f16x8 global read) and store 16B chunks.
  __syncthreads();
#pragma unroll
  for (int c = 0; c < 4; ++c) {
    const int col = c * 16 + lr;                // 0..63
    const float bnv = bias[n0 + col];
    const float bgv = bias[HD + n0 + col];
#pragma unroll
    for (int r = 0; r < 4; ++r)
#pragma unroll
      for (int g = 0; g < 4; ++g) {
        const int row = wv * 64 + r * 16 + q * 4 + g;  // 0..255
        const int pc = (col >> 3) ^ (row & 7);
        const int a = row * 64 + pc * 8 + (col & 7);
        float nl = an[r][c][g] + bnv;
        nl = nl > 0.f ? nl : 0.f;
        SM[a] = (_Float16)nl;
        SM[16384 + a] = (_Float16)(ag[r][c][g] + bgv);
      }
  }
  __syncthreads();
#pragma unroll
  for (int j = 0; j < 8; ++j) {
    const int cid = j * 256 + tid;
    const int row = cid >> 3;        // 0..255
    const int gc = cid & 7;
    const int pc = gc ^ (row & 7);
    f16x8 nl8 = *(const f16x8*)&SM[row * 64 + pc * 8];
    f16x8 gz8 = *(const f16x8*)&SM[16384 + row * 64 + pc * 8];
    const int xrow = m0 + row;
    f16x8 xv8 = *(const f16x8*)&x[(size_t)xrow * HD + n0 + gc * 8];
    f16x8 o8;
    float of[8];
#pragma unroll
    for (int e = 0; e < 8; ++e) {
      const float gt = 1.f / (1.f + __expf(-(float)gz8[e]));
      const float o = gt * (float)xv8[e] + (1.f - gt) * (float)nl8[e];
      of[e] = o;
      o8[e] = (_Float16)o;
    }
    if (mode == 0) {
      *(f16x8*)&oh[(size_t)xrow * HD + n0 + gc * 8] = o8;
    } else {
      if (mode == 1) {
        const int bb = xrow >> 9, tt = xrow & (SQ - 1);
        *(f16x8*)&oh[((size_t)(bb * PROW + WID + tt)) * HD + n0 + gc * 8] = o8;
      }
      float* op = out32 + (size_t)xrow * (2 * HD) + dir * HD + n0 + gc * 8;
      *(float4*)op = make_float4(of[0], of[1], of[2], of[3]);
      *(float4*)(op + 4) = make_float4(of[4], of[5], of[6], of[7]);
    }
  }
}

// ---------------------------------------------------------------------------
extern "C" void kernel_launch(void* const* d_in, const int* in_sizes, int n_in,
                              void* d_out, int out_size, void* d_ws, size_t ws_size,
                              hipStream_t stream) {
  const float* inputs   = (const float*)d_in[0];
  // d_in[1] = mask (all ones, unused by reference math)
  const float* fwd_pads = (const float*)d_in[2];   // [3][4][512]
  const float* bwd_pads = (const float*)d_in[3];
  const float* fwd_W    = (const float*)d_in[4];   // [3][2560][512]
  const float* fwd_b    = (const float*)d_in[5];   // [3][512]
  const float* bwd_W    = (const float*)d_in[6];
  const float* bwd_b    = (const float*)d_in[7];
  const float* fwd_hw_W = (const float*)d_in[8];   // [3][2][512][1024]
  const float* fwd_hw_b = (const float*)d_in[9];   // [3][2][1024]
  const float* bwd_hw_W = (const float*)d_in[10];
  const float* bwd_hw_b = (const float*)d_in[11];
  float* out = (float*)d_out;

  char* p = (char*)d_ws;
  auto take = [&](size_t n) { char* r = p; p += (n + 255) & ~(size_t)255; return r; };

  _Float16* padF = (_Float16*)take((size_t)LAY * PSTR * 2);   // per-layer pad bufs
  _Float16* padB = (_Float16*)take((size_t)LAY * PSTR * 2);
  _Float16* tF   = (_Float16*)take((size_t)MR * HD * 2);
  _Float16* tB   = (_Float16*)take((size_t)MR * HD * 2);
  _Float16* uF   = (_Float16*)take((size_t)MR * HD * 2);
  _Float16* uB   = (_Float16*)take((size_t)MR * HD * 2);
  _Float16* WtcF = (_Float16*)take((size_t)LAY * HD * KIN * 2);
  _Float16* WtcB = (_Float16*)take((size_t)LAY * HD * KIN * 2);
  _Float16* WthF = (_Float16*)take((size_t)LAY * 2 * (2 * HD) * HD * 2);
  _Float16* WthB = (_Float16*)take((size_t)LAY * 2 * (2 * HD) * HD * 2);

  // Weight transpose+convert (fp32 -> fp16, [R][C] -> [C][R] per slice)
  transpose_w2<<<dim3(HD / 32, KIN / 32, 2 * LAY), dim3(32, 8), 0, stream>>>(
      fwd_W, bwd_W, WtcF, WtcB, KIN, HD, LAY);
  transpose_w2<<<dim3((2 * HD) / 32, HD / 32, 2 * LAY * 2), dim3(32, 8), 0, stream>>>(
      fwd_hw_W, bwd_hw_W, WthF, WthB, HD, 2 * HD, LAY * 2);

  // Layer-0 activations into layer-0 pad interiors; all border rows once
  init_interior<<<(NB * SQ * HD / 4) / 256, 256, 0, stream>>>((const float4*)inputs, padF, padB);
  fill_all_pads<<<(LAY * 2 * NB * WID * HD) / 256, 256, 0, stream>>>(fwd_pads, bwd_pads, padF, padB);

  for (int i = 0; i < LAY; ++i) {
    _Float16* pF = padF + (size_t)i * PSTR;
    _Float16* pB = padB + (size_t)i * PSTR;
    const int nx = (i + 1 < LAY) ? (i + 1) : 0;   // dummy for last layer (mode 2)
    _Float16* nF = padF + (size_t)nx * PSTR;
    _Float16* nB = padB + (size_t)nx * PSTR;

    conv_gemm<<<dim3(1024), 256, 0, stream>>>(
        pF, pB,
        WtcF + (size_t)i * HD * KIN, WtcB + (size_t)i * HD * KIN,
        fwd_b + (size_t)i * HD, bwd_b + (size_t)i * HD, tF, tB);
    hw_gemm<<<dim3(1024), 256, 0, stream>>>(
        tF, tB,
        WthF + (size_t)(i * 2 + 0) * (2 * HD) * HD, WthB + (size_t)(i * 2 + 0) * (2 * HD) * HD,
        fwd_hw_b + (size_t)(i * 2 + 0) * (2 * HD), bwd_hw_b + (size_t)(i * 2 + 0) * (2 * HD),
        uF, uB, nullptr, 0);
    hw_gemm<<<dim3(1024), 256, 0, stream>>>(
        uF, uB,
        WthF + (size_t)(i * 2 + 1) * (2 * HD) * HD, WthB + (size_t)(i * 2 + 1) * (2 * HD) * HD,
        fwd_hw_b + (size_t)(i * 2 + 1) * (2 * HD), bwd_hw_b + (size_t)(i * 2 + 1) * (2 * HD),
        nF, nB, out + (size_t)i * MR * (2 * HD), (i + 1 < LAY) ? 1 : 2);
  }
}